// Round 5
// baseline (79.158 us; speedup 1.0000x reference)
//
#include <hip/hip_runtime.h>
#include <math.h>

// AntiAliasInterpolation2d: depthwise 13x13 gaussian blur + 4x nearest downsample,
// fused so only the 128x128 sampled output rows/cols are ever computed.
//
// x: (8, 512, 512, 32) f32 NHWC.  out: (8, 128, 128, 32) f32.
// Separable: out(r,c) = sum_i w[i] * sum_j w[j] * x(4r+i-6, 4c+j-6), zero-padded.
//
// R5 changes vs R4 (53.6us; calibrated model: 45.3us mandatory-HBM floor +
// ~3.4us L2 halo + overhead):
//  - TR 8 -> 16 with 512-THREAD blocks: row-halo amp 41/32 -> 73/64. Threads =
//    32 col-workers x 8 ch-groups x 2 row-halves; each half owns 8 of the 16
//    acc rows (h-blur duplicated, cheap). Wave lane layout (ch4=lane&7,
//    cw=lane>>3) identical to R4 -> proven LDS swizzle unchanged.
//  - Grid 256 blocks = 1/CU, 8 waves/CU. Serpentine sweep + XCD swizzle kept.

#define HH 512
#define WW 512
#define CC 32
#define OH 128
#define OW 128
#define KS 13
#define KA 6
#define TR 16            // output rows per block
#define TC 32            // output cols per block
#define NROWS (4*TR + 9) // 73 input row-steps per block (incl. halo)
#define NPX  144         // staged pixels per row (4*TC + 9 halo, padded to 144)
#define BUF_F4 (NPX*8)   // 1152 float4 slots per LDS row buffer (18432 B)
#define NTHR 512

struct W13 { float w[KS]; };

__device__ __forceinline__ int swz(int p, int c) {
    return p * 8 + (c ^ ((p >> 2) & 7));   // float4-slot index in a row buffer
}

__global__ __launch_bounds__(NTHR, 1)
void aa_blur_down_kernel(const float* __restrict__ x, float* __restrict__ out, W13 wk)
{
    __shared__ float4 lbuf[2][BUF_F4];
    __shared__ float WV[NROWS][TR];   // vertical weight (local input row, local output row)

    const int tid = threadIdx.x;

    // XCD-aware bijective swizzle: 256 blocks = 8 XCDs x 32. Consecutive lids
    // (rt-neighbors, sharing 9-row halos) land on the same XCD's L2.
    int bid = blockIdx.x;
    int lid = (bid & 7) * 32 + (bid >> 3);
    int rt = lid & 7;           // row tile   (8)
    int ct = (lid >> 3) & 3;    // col tile   (4)
    int n  = lid >> 5;          // batch      (8)

    const int r0 = rt * TR;
    const int y0 = 4 * r0 - KA;        // input row of local row-step 0
    const int cb = ct * (4 * TC) - KA; // input col of staged pixel 0

    // Vertical-weight table; row validity (zero padding) folded into the weight.
    for (int idx = tid; idx < NROWS * TR; idx += NTHR) {
        int yl = idx >> 4;            // /TR
        int r  = idx & (TR - 1);      // %TR
        int i  = yl - 4 * r;          // vertical tap index
        int y  = y0 + yl;
        bool ok = (i >= 0) && (i < KS) && ((unsigned)y < (unsigned)HH);
        WV[yl][r] = ok ? wk.w[i < 0 ? 0 : (i >= KS ? KS - 1 : i)] : 0.0f;
    }

    const int ch4 = tid & 7;          // float4 group of the 32 channels
    const int cw  = (tid >> 3) & 31;  // 0..31 output-column worker
    const int rh  = tid >> 8;         // 0/1: which 8-row half of the tile
    const int c   = ct * TC + cw;

    const float* xn = x + (size_t)n * HH * WW * CC;

    float4 acc[8];
#pragma unroll
    for (int r = 0; r < 8; ++r) acc[r] = make_float4(0.f, 0.f, 0.f, 0.f);

    // Serpentine: even rt sweeps top->bottom, odd rt bottom->top, so halo rows
    // shared with the vertical neighbor are touched at the same sweep phase.
    const bool up  = (rt & 1);
    const int  ylS = up ? (NROWS - 1) : 0;
    const int  dir = up ? -1 : 1;

    // ---- staging helpers ----
    // Each row-step stages BUF_F4=1152 float4: thread t handles f = t + 512k.
    // k<2 always valid; k=2 only for t<128.
#define STAGE_LOAD(SV, YL)                                                      \
    {                                                                           \
        int y  = y0 + (YL);                                                     \
        int yc = y < 0 ? 0 : (y >= HH ? HH - 1 : y);                            \
        const float* row = xn + (size_t)yc * (WW * CC);                         \
        _Pragma("unroll")                                                       \
        for (int k = 0; k < 3; ++k) {                                           \
            int f  = tid + NTHR * k;                                            \
            int p  = f >> 3;                                                    \
            int cc = f & 7;                                                     \
            int gx = cb + p;                                                    \
            bool ok = (f < BUF_F4) && ((unsigned)gx < (unsigned)WW);            \
            int gxc = gx < 0 ? 0 : (gx >= WW ? WW - 1 : gx);                    \
            float4 v = *reinterpret_cast<const float4*>(row + (size_t)gxc * CC + cc * 4); \
            SV[k] = ok ? v : make_float4(0.f, 0.f, 0.f, 0.f);                   \
        }                                                                       \
    }

#define STAGE_WRITE(B, SV)                                                      \
    {                                                                           \
        _Pragma("unroll")                                                       \
        for (int k = 0; k < 3; ++k) {                                           \
            int f = tid + NTHR * k;                                             \
            if (k < 2 || f < BUF_F4) {                                          \
                int p  = f >> 3;                                                \
                int cc = f & 7;                                                 \
                lbuf[B][swz(p, cc)] = SV[k];                                    \
            }                                                                   \
        }                                                                       \
    }

    // prologue: stage first row-step into buffer 0
    {
        float4 sv[3];
        STAGE_LOAD(sv, ylS);
        STAGE_WRITE(0, sv);
    }
    __syncthreads();

    int cur = 0;
    for (int s = 0; s < NROWS; ++s) {
        const int yl = ylS + dir * s;
        float4 sv[3];
        const bool more = (s + 1 < NROWS);
        if (more) STAGE_LOAD(sv, yl + dir);   // issue next-row loads early (T14)

        // horizontal blur from LDS (swizzled, conflict-free)
        float4 h = make_float4(0.f, 0.f, 0.f, 0.f);
#pragma unroll
        for (int j = 0; j < KS; ++j) {
            int p = 4 * cw + j;
            float4 v = lbuf[cur][swz(p, ch4)];
            float wj = wk.w[j];
            h.x = fmaf(wj, v.x, h.x);
            h.y = fmaf(wj, v.y, h.y);
            h.z = fmaf(wj, v.z, h.z);
            h.w = fmaf(wj, v.w, h.w);
        }

        // vertical accumulate into this half's 8 output rows
#pragma unroll
        for (int r = 0; r < 8; ++r) {
            float wv = WV[yl][rh * 8 + r];   // uniform-address LDS read -> broadcast
            acc[r].x = fmaf(wv, h.x, acc[r].x);
            acc[r].y = fmaf(wv, h.y, acc[r].y);
            acc[r].z = fmaf(wv, h.z, acc[r].z);
            acc[r].w = fmaf(wv, h.w, acc[r].w);
        }

        if (more) STAGE_WRITE(cur ^ 1, sv); // write-late into the other buffer
        __syncthreads();
        cur ^= 1;
    }

#pragma unroll
    for (int r = 0; r < 8; ++r) {
        float* o = out + (((size_t)n * OH + (r0 + rh * 8 + r)) * OW + c) * CC + ch4 * 4;
        *reinterpret_cast<float4*>(o) = acc[r];
    }
}

extern "C" void kernel_launch(void* const* d_in, const int* in_sizes, int n_in,
                              void* d_out, int out_size, void* d_ws, size_t ws_size,
                              hipStream_t stream)
{
    const float* x = (const float*)d_in[0];
    float* out = (float*)d_out;

    // Rebuild the separable gaussian weights on the host (double precision).
    // Reference: g[i]=exp(-(i-6)^2/(2*1.5^2)); w[i]=g[i]/sum(g); k2=outer(w,w).
    W13 wk;
    double g[KS], s = 0.0;
    for (int i = 0; i < KS; ++i) {
        double d = i - (KS - 1) / 2.0;
        g[i] = exp(-(d * d) / (2.0 * 1.5 * 1.5));
        s += g[i];
    }
    for (int i = 0; i < KS; ++i) wk.w[i] = (float)(g[i] / s);

    dim3 grid(8 * 4 * 8);   // batch x col-tiles x row-tiles = 256 blocks
    aa_blur_down_kernel<<<grid, NTHR, 0, stream>>>(x, out, wk);
}

// Round 6
// 52.422 us; speedup vs baseline: 1.5100x; 1.5100x over previous
//
#include <hip/hip_runtime.h>
#include <math.h>

// AntiAliasInterpolation2d: depthwise 13x13 gaussian blur + 4x nearest downsample,
// fused so only the 128x128 sampled output rows/cols are ever computed.
//
// x: (8, 512, 512, 32) f32 NHWC.  out: (8, 128, 128, 32) f32.
// Separable: out(r,c) = sum_i w[i] * sum_j w[j] * x(4r+i-6, 4c+j-6), zero-padded.
//
// R6 changes vs R4 (53.6us) / R5 (79us FAILED, 1 block/CU barrier exposure):
//  - WAVE-PRIVATE staging: each wave owns an 8-col x 8-row output tile and its
//    own LDS double-buffer. NO __syncthreads in the main loop (same-wave LDS
//    ordering is lgkmcnt-automatic) -> waves self-pace, no all-wave drain per
//    row-step. 8 waves/CU keep loads continuously in flight.
//  - Geometry back to R4: 512 blocks (2/CU), 256 threads, serpentine sweep,
//    XCD swizzle, XOR bank swizzle (re-verified for the new lane mapping:
//    every 16-lane phase touches each bank <= 2x = free per m136).

#define HH 512
#define WW 512
#define CC 32
#define OH 128
#define OW 128
#define KS 13
#define KA 6
#define TR 8               // output rows per wave
#define TCW 8              // output cols per wave
#define NROWS (4*TR + 9)   // 41 input row-steps
#define NPXW 41            // needed pixels per wave-row (4*TCW+9)
#define NPXP 48            // padded to 6 wave-loads of 8 px
#define SLOTS (NPXP*8)     // 384 float4 per buffer (6144 B)

struct W13 { float w[KS]; };

__device__ __forceinline__ int swz(int p, int c) {
    return p * 8 + (c ^ ((p >> 2) & 7));   // float4-slot index in a row buffer
}

__global__ __launch_bounds__(256, 2)
void aa_blur_down_kernel(const float* __restrict__ x, float* __restrict__ out, W13 wk)
{
    __shared__ float4 lbuf[4][2][SLOTS];   // per-wave double buffers (48 KB)
    __shared__ float WV[NROWS][TR];        // vertical weights (shared, read-only)

    const int tid  = threadIdx.x;
    const int wid  = tid >> 6;
    const int lane = tid & 63;

    // XCD-aware bijective swizzle: 512 blocks = 8 XCDs x 64. Consecutive lids
    // are rt-neighbors on the same XCD (phase-aligned halo -> L2 hits).
    int bid = blockIdx.x;
    int lid = (bid & 7) * 64 + (bid >> 3);
    int rt  = lid & 15;          // row tile   (16)
    int ctb = (lid >> 4) & 3;    // col block  (4)  -> 4 waves = 32 cols
    int n   = lid >> 6;          // batch      (8)

    const int r0 = rt * TR;
    const int y0 = 4 * r0 - KA;  // input row of local row-step 0

    // Vertical-weight table; row validity (zero padding) folded into the weight.
    for (int idx = tid; idx < NROWS * TR; idx += 256) {
        int yl = idx >> 3;
        int r  = idx & (TR - 1);
        int i  = yl - 4 * r;
        int y  = y0 + yl;
        bool ok = (i >= 0) && (i < KS) && ((unsigned)y < (unsigned)HH);
        WV[yl][r] = ok ? wk.w[i < 0 ? 0 : (i >= KS ? KS - 1 : i)] : 0.0f;
    }
    __syncthreads();             // the ONLY barrier

    const int ch4 = lane & 7;    // float4 group of the 32 channels
    const int cwL = lane >> 3;   // 0..7 col worker within the wave
    const int cw0 = (ctb * 4 + wid) * TCW;  // wave's first output col
    const int c   = cw0 + cwL;
    const int cb  = 4 * cw0 - KA;           // input col of wave-local px 0
    const int psub = lane >> 3;  // staging pixel sub-index (same split as cwL)

    const float* xn = x + (size_t)n * HH * WW * CC;

    float4 acc[TR];
#pragma unroll
    for (int r = 0; r < TR; ++r) acc[r] = make_float4(0.f, 0.f, 0.f, 0.f);

    // Serpentine: even rt sweeps top->bottom, odd rt bottom->top, so halo rows
    // shared with the vertical neighbor are touched at the same sweep phase.
    const bool up  = (rt & 1);
    const int  ylS = up ? (NROWS - 1) : 0;
    const int  dir = up ? -1 : 1;

    // ---- wave-private staging: 6 coalesced wave-loads cover 48 px x 8 ch ----
#define STAGE_LOAD(SV, YL)                                                          \
    {                                                                               \
        int y  = y0 + (YL);                                                         \
        int yc = y < 0 ? 0 : (y >= HH ? HH - 1 : y);                                \
        const float* row = xn + (size_t)yc * (WW * CC);                             \
        _Pragma("unroll")                                                           \
        for (int it = 0; it < 6; ++it) {                                            \
            int p  = it * 8 + psub;                                                 \
            int gx = cb + p;                                                        \
            bool ok = (p < NPXW) && ((unsigned)gx < (unsigned)WW);                  \
            int gxc = gx < 0 ? 0 : (gx >= WW ? WW - 1 : gx);                        \
            float4 v = *reinterpret_cast<const float4*>(row + (size_t)gxc * CC + ch4 * 4); \
            SV[it] = ok ? v : make_float4(0.f, 0.f, 0.f, 0.f);                      \
        }                                                                           \
    }

#define STAGE_WRITE(B, SV)                                                          \
    {                                                                               \
        _Pragma("unroll")                                                           \
        for (int it = 0; it < 6; ++it) {                                            \
            int p = it * 8 + psub;                                                  \
            lbuf[wid][B][swz(p, ch4)] = SV[it];                                     \
        }                                                                           \
    }

    // prologue: stage first row-step into buffer 0
    {
        float4 sv[6];
        STAGE_LOAD(sv, ylS);
        STAGE_WRITE(0, sv);
    }

    int cur = 0;
    for (int s = 0; s < NROWS; ++s) {
        const int yl = ylS + dir * s;
        float4 sv[6];
        const bool more = (s + 1 < NROWS);
        if (more) STAGE_LOAD(sv, yl + dir);   // issue next-row loads early (T14)

        // horizontal blur from this wave's LDS buffer (swizzled, conflict-free)
        float4 h = make_float4(0.f, 0.f, 0.f, 0.f);
#pragma unroll
        for (int j = 0; j < KS; ++j) {
            int p = 4 * cwL + j;
            float4 v = lbuf[wid][cur][swz(p, ch4)];
            float wj = wk.w[j];
            h.x = fmaf(wj, v.x, h.x);
            h.y = fmaf(wj, v.y, h.y);
            h.z = fmaf(wj, v.z, h.z);
            h.w = fmaf(wj, v.w, h.w);
        }

        // vertical accumulate into the wave's 8 output rows
#pragma unroll
        for (int r = 0; r < TR; ++r) {
            float wv = WV[yl][r];    // uniform-address LDS read -> broadcast
            acc[r].x = fmaf(wv, h.x, acc[r].x);
            acc[r].y = fmaf(wv, h.y, acc[r].y);
            acc[r].z = fmaf(wv, h.z, acc[r].z);
            acc[r].w = fmaf(wv, h.w, acc[r].w);
        }

        if (more) STAGE_WRITE(cur ^ 1, sv);   // write-late into the other buffer
        cur ^= 1;                             // NO barrier: wave-private buffer
    }

#pragma unroll
    for (int r = 0; r < TR; ++r) {
        float* o = out + (((size_t)n * OH + (r0 + r)) * OW + c) * CC + ch4 * 4;
        *reinterpret_cast<float4*>(o) = acc[r];
    }
}

extern "C" void kernel_launch(void* const* d_in, const int* in_sizes, int n_in,
                              void* d_out, int out_size, void* d_ws, size_t ws_size,
                              hipStream_t stream)
{
    const float* x = (const float*)d_in[0];
    float* out = (float*)d_out;

    // Rebuild the separable gaussian weights on the host (double precision).
    // Reference: g[i]=exp(-(i-6)^2/(2*1.5^2)); w[i]=g[i]/sum(g); k2=outer(w,w).
    W13 wk;
    double g[KS], s = 0.0;
    for (int i = 0; i < KS; ++i) {
        double d = i - (KS - 1) / 2.0;
        g[i] = exp(-(d * d) / (2.0 * 1.5 * 1.5));
        s += g[i];
    }
    for (int i = 0; i < KS; ++i) wk.w[i] = (float)(g[i] / s);

    dim3 grid(8 * 4 * 16);   // batch x col-blocks x row-tiles = 512 blocks
    aa_blur_down_kernel<<<grid, 256, 0, stream>>>(x, out, wk);
}